// Round 1
// baseline (925.125 us; speedup 1.0000x reference)
//
#include <hip/hip_runtime.h>
#include <math.h>

#define NEG_SLOPE 0.2f

__device__ __forceinline__ float lrelu(float v) { return v > 0.0f ? v : NEG_SLOPE * v; }

// ---------------- CSR build ----------------

__global__ void count_dst_k(const int* __restrict__ dst, int* __restrict__ counts, int e) {
  int i = blockIdx.x * 256 + threadIdx.x;
  if (i < e) atomicAdd(&counts[dst[i]], 1);
}

// Single-block exclusive scan over counts; writes row_ptr[0..n] and resets
// cnt_cursor[i] to the start offset (used as the scatter cursor).
__global__ void scan_k(int* __restrict__ cnt_cursor, int* __restrict__ row_ptr, int n) {
  __shared__ int part[1024];
  const int tid = threadIdx.x;
  const int chunk = (n + 1023) / 1024;
  const int base = tid * chunk;
  int sum = 0;
  for (int i = 0; i < chunk; ++i) {
    int idx = base + i;
    if (idx < n) sum += cnt_cursor[idx];
  }
  part[tid] = sum;
  __syncthreads();
  for (int o = 1; o < 1024; o <<= 1) {
    int t = (tid >= o) ? part[tid - o] : 0;
    __syncthreads();
    part[tid] += t;
    __syncthreads();
  }
  int run = part[tid] - sum;  // exclusive prefix of this thread's chunk
  for (int i = 0; i < chunk; ++i) {
    int idx = base + i;
    if (idx < n) {
      int c = cnt_cursor[idx];
      row_ptr[idx] = run;
      cnt_cursor[idx] = run;
      run += c;
    }
  }
  if (tid == 1023) row_ptr[n] = part[1023];
}

__global__ void scatter_k(const int* __restrict__ src, const int* __restrict__ dst,
                          int* __restrict__ cursor, int* __restrict__ csr, int e) {
  int i = blockIdx.x * 256 + threadIdx.x;
  if (i < e) {
    int pos = atomicAdd(&cursor[dst[i]], 1);
    csr[pos] = src[i];
  }
}

// ---------------- GEMM: Y[n,M] = X[n,128] @ W[128,M] ----------------
// Block computes 64 rows x M cols. K chunked by 32 through LDS.

template<int M>
__global__ __launch_bounds__(256) void gemm_k(const float* __restrict__ X,
                                              const float* __restrict__ W,
                                              float* __restrict__ Y, int n) {
  constexpr int NC4 = M / 4;        // col quads per row: 32 (M=128) or 16 (M=64)
  constexpr int NTY = 256 / NC4;    // row groups: 8 or 16
  constexpr int RPT = 64 / NTY;     // rows per thread: 8 or 4
  __shared__ float4 ws4[32 * NC4];  // [k within chunk][col quad]
  __shared__ float4 xs4[64 * 8];    // [row][k quad within chunk]
  const int tid = threadIdx.x;
  const int tx = tid % NC4;
  const int ty = tid / NC4;
  const int rb = blockIdx.x * 64;
  float acc[RPT][4];
  for (int i = 0; i < RPT; ++i)
    for (int j = 0; j < 4; ++j) acc[i][j] = 0.f;

  for (int kc = 0; kc < 4; ++kc) {
    const float4* Wp = (const float4*)(W + (size_t)kc * 32 * M);
    for (int i = tid; i < 32 * NC4; i += 256) ws4[i] = Wp[i];
    for (int i = tid; i < 64 * 8; i += 256) {
      int r = i >> 3, c4 = i & 7;
      int row = rb + r;
      float4 v = make_float4(0.f, 0.f, 0.f, 0.f);
      if (row < n) v = *(const float4*)(X + (size_t)row * 128 + kc * 32 + c4 * 4);
      xs4[i] = v;
    }
    __syncthreads();
    for (int k4 = 0; k4 < 8; ++k4) {
      float4 xv[RPT];
      for (int i = 0; i < RPT; ++i) xv[i] = xs4[(ty + i * NTY) * 8 + k4];
      float4 wv[4];
      for (int dk = 0; dk < 4; ++dk) wv[dk] = ws4[(k4 * 4 + dk) * NC4 + tx];
      for (int i = 0; i < RPT; ++i) {
        acc[i][0] += xv[i].x * wv[0].x + xv[i].y * wv[1].x + xv[i].z * wv[2].x + xv[i].w * wv[3].x;
        acc[i][1] += xv[i].x * wv[0].y + xv[i].y * wv[1].y + xv[i].z * wv[2].y + xv[i].w * wv[3].y;
        acc[i][2] += xv[i].x * wv[0].z + xv[i].y * wv[1].z + xv[i].z * wv[2].z + xv[i].w * wv[3].z;
        acc[i][3] += xv[i].x * wv[0].w + xv[i].y * wv[1].w + xv[i].z * wv[2].w + xv[i].w * wv[3].w;
      }
    }
    __syncthreads();
  }
  for (int i = 0; i < RPT; ++i) {
    int row = rb + ty + i * NTY;
    if (row < n)
      *(float4*)(Y + (size_t)row * M + tx * 4) =
          make_float4(acc[i][0], acc[i][1], acc[i][2], acc[i][3]);
  }
}

// ---------------- attention coefficients: s/d per (node,head) ----------------

template<int H_>
__global__ __launch_bounds__(256) void attn_k(const float* __restrict__ xl,
                                              const float* __restrict__ a_src,
                                              const float* __restrict__ a_dst,
                                              float* __restrict__ sArr,
                                              float* __restrict__ dArr, int n) {
  const int pair = blockIdx.x * 4 + (threadIdx.x >> 6);  // pair = node*H_ + h
  const int lane = threadIdx.x & 63;
  if (pair >= n * H_) return;
  const int h = pair % H_;
  float v = xl[(size_t)pair * 64 + lane];
  float sv = v * a_src[h * 64 + lane];
  float dv = v * a_dst[h * 64 + lane];
  for (int o = 32; o > 0; o >>= 1) {
    sv += __shfl_xor(sv, o);
    dv += __shfl_xor(dv, o);
  }
  if (lane == 0) {
    sArr[pair] = sv;
    dArr[pair] = dv;
  }
}

// ---------------- softmax + aggregation: one wave per (node,head) ----------------
// Self-loop handled analytically (src=dst=node).

template<int H_, bool DO_ELU>
__global__ __launch_bounds__(256) void aggr_k(const float* __restrict__ xl,
                                              const float* __restrict__ sArr,
                                              const float* __restrict__ dArr,
                                              const float* __restrict__ bias,
                                              const int* __restrict__ row_ptr,
                                              const int* __restrict__ csr,
                                              float* __restrict__ outp, int n) {
  const int pair = blockIdx.x * 4 + (threadIdx.x >> 6);
  const int lane = threadIdx.x & 63;  // lane == channel
  if (pair >= n * H_) return;
  const int nn = pair / H_;
  const int h = pair - nn * H_;
  const int row = row_ptr[nn];
  const int deg = row_ptr[nn + 1] - row;
  const float dn = dArr[pair];
  const float sn = sArr[pair];
  const float eself = lrelu(sn + dn);

  // pass 1: max (lane-parallel over edges)
  float m = eself;
  for (int j = lane; j < deg; j += 64) {
    int sj = csr[row + j];
    m = fmaxf(m, lrelu(sArr[sj * H_ + h] + dn));
  }
  for (int o = 32; o > 0; o >>= 1) m = fmaxf(m, __shfl_xor(m, o));

  // pass 2: denom
  float sum = 0.f;
  for (int j = lane; j < deg; j += 64) {
    int sj = csr[row + j];
    sum += __expf(lrelu(sArr[sj * H_ + h] + dn) - m);
  }
  for (int o = 32; o > 0; o >>= 1) sum += __shfl_xor(sum, o);
  sum += __expf(eself - m);
  const float inv = 1.0f / sum;

  // pass 3: weighted gather, lanes = channels
  float acc = __expf(eself - m) * inv * xl[(size_t)pair * 64 + lane];
  for (int j = 0; j < deg; ++j) {
    int sj = csr[row + j];  // uniform across lanes -> broadcast load
    float w = __expf(lrelu(sArr[sj * H_ + h] + dn) - m) * inv;
    acc += w * xl[((size_t)sj * H_ + h) * 64 + lane];
  }
  float val = acc + bias[h * 64 + lane];
  if (DO_ELU) val = val > 0.f ? val : expm1f(val);
  outp[(size_t)pair * 64 + lane] = val;
}

// ---------------- launch ----------------

extern "C" void kernel_launch(void* const* d_in, const int* in_sizes, int n_in,
                              void* d_out, int out_size, void* d_ws, size_t ws_size,
                              hipStream_t stream) {
  const float* x  = (const float*)d_in[0];
  const int* ei   = (const int*)d_in[1];
  const float* W0 = (const float*)d_in[2];
  const float* as0 = (const float*)d_in[3];
  const float* ad0 = (const float*)d_in[4];
  const float* b0 = (const float*)d_in[5];
  const float* W1 = (const float*)d_in[6];
  const float* as1 = (const float*)d_in[7];
  const float* ad1 = (const float*)d_in[8];
  const float* b1 = (const float*)d_in[9];
  const float* W2 = (const float*)d_in[10];
  const float* as2 = (const float*)d_in[11];
  const float* ad2 = (const float*)d_in[12];
  const float* b2 = (const float*)d_in[13];
  float* out = (float*)d_out;

  const int n = in_sizes[0] / 128;
  const int e = in_sizes[1] / 2;
  const int* srcIdx = ei;
  const int* dstIdx = ei + e;

  float* ws = (float*)d_ws;
  float* bufA = ws;                                // n*128  (xl of current layer)
  float* bufB = bufA + (size_t)n * 128;            // n*128  (layer output)
  float* sArr = bufB + (size_t)n * 128;            // n*2
  float* dArr = sArr + (size_t)n * 2;              // n*2
  int* row_ptr = (int*)(dArr + (size_t)n * 2);     // n+1
  int* cursor = row_ptr + (n + 1);                 // n
  int* csr = cursor + n;                           // e

  // CSR build (shared by all 3 layers)
  hipMemsetAsync(cursor, 0, (size_t)n * sizeof(int), stream);
  count_dst_k<<<(e + 255) / 256, 256, 0, stream>>>(dstIdx, cursor, e);
  scan_k<<<1, 1024, 0, stream>>>(cursor, row_ptr, n);
  scatter_k<<<(e + 255) / 256, 256, 0, stream>>>(srcIdx, dstIdx, cursor, csr, e);

  const int gb = (n + 63) / 64;
  const int gp2 = (n * 2 + 3) / 4;  // H=2 pair-grid
  const int gp1 = (n + 3) / 4;      // H=1 pair-grid

  // layer 0: x -> bufA (xl) -> bufB (elu(out))
  gemm_k<128><<<gb, 256, 0, stream>>>(x, W0, bufA, n);
  attn_k<2><<<gp2, 256, 0, stream>>>(bufA, as0, ad0, sArr, dArr, n);
  aggr_k<2, true><<<gp2, 256, 0, stream>>>(bufA, sArr, dArr, b0, row_ptr, csr, bufB, n);

  // layer 1: bufB -> bufA (xl) -> bufB
  gemm_k<128><<<gb, 256, 0, stream>>>(bufB, W1, bufA, n);
  attn_k<2><<<gp2, 256, 0, stream>>>(bufA, as1, ad1, sArr, dArr, n);
  aggr_k<2, true><<<gp2, 256, 0, stream>>>(bufA, sArr, dArr, b1, row_ptr, csr, bufB, n);

  // layer 2: bufB -> bufA (xl, M=64) -> d_out
  gemm_k<64><<<gb, 256, 0, stream>>>(bufB, W2, bufA, n);
  attn_k<1><<<gp1, 256, 0, stream>>>(bufA, as2, ad2, sArr, dArr, n);
  aggr_k<1, false><<<gp1, 256, 0, stream>>>(bufA, sArr, dArr, b2, row_ptr, csr, out, n);
}

// Round 2
// 699.836 us; speedup vs baseline: 1.3219x; 1.3219x over previous
//
#include <hip/hip_runtime.h>
#include <math.h>

#define NEG_SLOPE 0.2f

__device__ __forceinline__ float lrelu(float v) { return v > 0.0f ? v : NEG_SLOPE * v; }

// ---------------- CSR build ----------------

__global__ void count_dst_k(const int* __restrict__ dst, int* __restrict__ counts, int e) {
  int i = blockIdx.x * 256 + threadIdx.x;
  if (i < e) atomicAdd(&counts[dst[i]], 1);
}

__global__ void scan_k(int* __restrict__ cnt_cursor, int* __restrict__ row_ptr, int n) {
  __shared__ int part[1024];
  const int tid = threadIdx.x;
  const int chunk = (n + 1023) / 1024;
  const int base = tid * chunk;
  int sum = 0;
  for (int i = 0; i < chunk; ++i) {
    int idx = base + i;
    if (idx < n) sum += cnt_cursor[idx];
  }
  part[tid] = sum;
  __syncthreads();
  for (int o = 1; o < 1024; o <<= 1) {
    int t = (tid >= o) ? part[tid - o] : 0;
    __syncthreads();
    part[tid] += t;
    __syncthreads();
  }
  int run = part[tid] - sum;
  for (int i = 0; i < chunk; ++i) {
    int idx = base + i;
    if (idx < n) {
      int c = cnt_cursor[idx];
      row_ptr[idx] = run;
      cnt_cursor[idx] = run;
      run += c;
    }
  }
  if (tid == 1023) row_ptr[n] = part[1023];
}

__global__ void scatter_k(const int* __restrict__ src, const int* __restrict__ dst,
                          int* __restrict__ cursor, int* __restrict__ csr, int e) {
  int i = blockIdx.x * 256 + threadIdx.x;
  if (i < e) {
    int pos = atomicAdd(&cursor[dst[i]], 1);
    csr[pos] = src[i];
  }
}

// ---------------- GEMM: Y[n,M] = X[n,128] @ W[128,M] ----------------

template<int M>
__global__ __launch_bounds__(256) void gemm_k(const float* __restrict__ X,
                                              const float* __restrict__ W,
                                              float* __restrict__ Y, int n) {
  constexpr int NC4 = M / 4;
  constexpr int NTY = 256 / NC4;
  constexpr int RPT = 64 / NTY;
  __shared__ float4 ws4[32 * NC4];
  __shared__ float4 xs4[64 * 8];
  const int tid = threadIdx.x;
  const int tx = tid % NC4;
  const int ty = tid / NC4;
  const int rb = blockIdx.x * 64;
  float acc[RPT][4];
  for (int i = 0; i < RPT; ++i)
    for (int j = 0; j < 4; ++j) acc[i][j] = 0.f;

  for (int kc = 0; kc < 4; ++kc) {
    const float4* Wp = (const float4*)(W + (size_t)kc * 32 * M);
    for (int i = tid; i < 32 * NC4; i += 256) ws4[i] = Wp[i];
    for (int i = tid; i < 64 * 8; i += 256) {
      int r = i >> 3, c4 = i & 7;
      int row = rb + r;
      float4 v = make_float4(0.f, 0.f, 0.f, 0.f);
      if (row < n) v = *(const float4*)(X + (size_t)row * 128 + kc * 32 + c4 * 4);
      xs4[i] = v;
    }
    __syncthreads();
    for (int k4 = 0; k4 < 8; ++k4) {
      float4 xv[RPT];
      for (int i = 0; i < RPT; ++i) xv[i] = xs4[(ty + i * NTY) * 8 + k4];
      float4 wv[4];
      for (int dk = 0; dk < 4; ++dk) wv[dk] = ws4[(k4 * 4 + dk) * NC4 + tx];
      for (int i = 0; i < RPT; ++i) {
        acc[i][0] += xv[i].x * wv[0].x + xv[i].y * wv[1].x + xv[i].z * wv[2].x + xv[i].w * wv[3].x;
        acc[i][1] += xv[i].x * wv[0].y + xv[i].y * wv[1].y + xv[i].z * wv[2].y + xv[i].w * wv[3].y;
        acc[i][2] += xv[i].x * wv[0].z + xv[i].y * wv[1].z + xv[i].z * wv[2].z + xv[i].w * wv[3].z;
        acc[i][3] += xv[i].x * wv[0].w + xv[i].y * wv[1].w + xv[i].z * wv[2].w + xv[i].w * wv[3].w;
      }
    }
    __syncthreads();
  }
  for (int i = 0; i < RPT; ++i) {
    int row = rb + ty + i * NTY;
    if (row < n)
      *(float4*)(Y + (size_t)row * M + tx * 4) =
          make_float4(acc[i][0], acc[i][1], acc[i][2], acc[i][3]);
  }
}

// ---------------- attention coefficients: s/d per (node,head) ----------------

template<int H_>
__global__ __launch_bounds__(256) void attn_k(const float* __restrict__ xl,
                                              const float* __restrict__ a_src,
                                              const float* __restrict__ a_dst,
                                              float* __restrict__ sArr,
                                              float* __restrict__ dArr, int n) {
  const int pair = blockIdx.x * 4 + (threadIdx.x >> 6);
  const int lane = threadIdx.x & 63;
  if (pair >= n * H_) return;
  const int h = pair % H_;
  float v = xl[(size_t)pair * 64 + lane];
  float sv = v * a_src[h * 64 + lane];
  float dv = v * a_dst[h * 64 + lane];
  for (int o = 32; o > 0; o >>= 1) {
    sv += __shfl_xor(sv, o);
    dv += __shfl_xor(dv, o);
  }
  if (lane == 0) {
    sArr[pair] = sv;
    dArr[pair] = dv;
  }
}

// ---------------- softmax precompute: unnormalized exp per edge + self + 1/denom ----

__global__ __launch_bounds__(256) void softmax2_k(const float* __restrict__ sArr,
                                                  const float* __restrict__ dArr,
                                                  const int* __restrict__ row_ptr,
                                                  const int* __restrict__ csr,
                                                  float* __restrict__ alphaE,
                                                  float* __restrict__ alphaSelf,
                                                  float* __restrict__ invArr, int n) {
  const int node = blockIdx.x * 4 + (threadIdx.x >> 6);
  const int lane = threadIdx.x & 63;
  if (node >= n) return;
  const int row = row_ptr[node];
  const int deg = row_ptr[node + 1] - row;
  const float2 dn = ((const float2*)dArr)[node];
  const float2 sn = ((const float2*)sArr)[node];
  const float e0s = lrelu(sn.x + dn.x), e1s = lrelu(sn.y + dn.y);
  float m0 = e0s, m1 = e1s;
  for (int j = lane; j < deg; j += 64) {
    int sj = csr[row + j];
    float2 sv = ((const float2*)sArr)[sj];
    m0 = fmaxf(m0, lrelu(sv.x + dn.x));
    m1 = fmaxf(m1, lrelu(sv.y + dn.y));
  }
  for (int o = 32; o > 0; o >>= 1) {
    m0 = fmaxf(m0, __shfl_xor(m0, o));
    m1 = fmaxf(m1, __shfl_xor(m1, o));
  }
  float s0 = 0.f, s1 = 0.f;
  for (int j = lane; j < deg; j += 64) {
    int sj = csr[row + j];
    float2 sv = ((const float2*)sArr)[sj];
    float x0 = __expf(lrelu(sv.x + dn.x) - m0);
    float x1 = __expf(lrelu(sv.y + dn.y) - m1);
    ((float2*)alphaE)[row + j] = make_float2(x0, x1);
    s0 += x0;
    s1 += x1;
  }
  for (int o = 32; o > 0; o >>= 1) {
    s0 += __shfl_xor(s0, o);
    s1 += __shfl_xor(s1, o);
  }
  float xs0 = __expf(e0s - m0), xs1 = __expf(e1s - m1);
  s0 += xs0;
  s1 += xs1;
  if (lane == 0) {
    ((float2*)alphaSelf)[node] = make_float2(xs0, xs1);
    ((float2*)invArr)[node] = make_float2(1.f / s0, 1.f / s1);
  }
}

__global__ __launch_bounds__(256) void softmax1_k(const float* __restrict__ sArr,
                                                  const float* __restrict__ dArr,
                                                  const int* __restrict__ row_ptr,
                                                  const int* __restrict__ csr,
                                                  float* __restrict__ alphaE,
                                                  float* __restrict__ alphaSelf,
                                                  float* __restrict__ invArr, int n) {
  const int node = blockIdx.x * 4 + (threadIdx.x >> 6);
  const int lane = threadIdx.x & 63;
  if (node >= n) return;
  const int row = row_ptr[node];
  const int deg = row_ptr[node + 1] - row;
  const float dn = dArr[node];
  const float es = lrelu(sArr[node] + dn);
  float m = es;
  for (int j = lane; j < deg; j += 64) {
    int sj = csr[row + j];
    m = fmaxf(m, lrelu(sArr[sj] + dn));
  }
  for (int o = 32; o > 0; o >>= 1) m = fmaxf(m, __shfl_xor(m, o));
  float s = 0.f;
  for (int j = lane; j < deg; j += 64) {
    int sj = csr[row + j];
    float x = __expf(lrelu(sArr[sj] + dn) - m);
    alphaE[row + j] = x;
    s += x;
  }
  for (int o = 32; o > 0; o >>= 1) s += __shfl_xor(s, o);
  float xs = __expf(es - m);
  s += xs;
  if (lane == 0) {
    alphaSelf[node] = xs;
    invArr[node] = 1.f / s;
  }
}

// ---------------- aggregation: one wave per node ----------------
// H=2: float2/lane covers both heads (row = 512B); lane<32 -> head0.

template<bool DO_ELU>
__global__ __launch_bounds__(256) void aggr2_k(const float* __restrict__ xl,
                                               const float* __restrict__ alphaE,
                                               const float* __restrict__ alphaSelf,
                                               const float* __restrict__ invArr,
                                               const float* __restrict__ bias,
                                               const int* __restrict__ row_ptr,
                                               const int* __restrict__ csr,
                                               float* __restrict__ outp, int n) {
  const int node = blockIdx.x * 4 + (threadIdx.x >> 6);
  const int lane = threadIdx.x & 63;
  if (node >= n) return;
  const int row = row_ptr[node];
  const int deg = row_ptr[node + 1] - row;
  const float2* __restrict__ xl2 = (const float2*)xl;
  const float2* __restrict__ aE = (const float2*)alphaE;
  const bool lo = lane < 32;
  float ax = 0.f, ay = 0.f, bx = 0.f, by = 0.f;
  int j = 0;
  for (; j + 4 <= deg; j += 4) {
    int s0 = csr[row + j], s1 = csr[row + j + 1], s2 = csr[row + j + 2], s3 = csr[row + j + 3];
    float2 a0 = aE[row + j], a1 = aE[row + j + 1], a2 = aE[row + j + 2], a3 = aE[row + j + 3];
    float2 v0 = xl2[(size_t)s0 * 64 + lane];
    float2 v1 = xl2[(size_t)s1 * 64 + lane];
    float2 v2 = xl2[(size_t)s2 * 64 + lane];
    float2 v3 = xl2[(size_t)s3 * 64 + lane];
    float w0 = lo ? a0.x : a0.y, w1 = lo ? a1.x : a1.y;
    float w2 = lo ? a2.x : a2.y, w3 = lo ? a3.x : a3.y;
    ax += w0 * v0.x; ay += w0 * v0.y;
    bx += w1 * v1.x; by += w1 * v1.y;
    ax += w2 * v2.x; ay += w2 * v2.y;
    bx += w3 * v3.x; by += w3 * v3.y;
  }
  for (; j < deg; ++j) {
    int sj = csr[row + j];
    float2 a = aE[row + j];
    float2 v = xl2[(size_t)sj * 64 + lane];
    float w = lo ? a.x : a.y;
    ax += w * v.x; ay += w * v.y;
  }
  // self loop
  float2 aS = ((const float2*)alphaSelf)[node];
  float2 vS = xl2[(size_t)node * 64 + lane];
  float wS = lo ? aS.x : aS.y;
  ax += wS * vS.x; ay += wS * vS.y;
  float2 iv = ((const float2*)invArr)[node];
  float wi = lo ? iv.x : iv.y;
  float2 bb = ((const float2*)bias)[lane];
  float rx = (ax + bx) * wi + bb.x;
  float ry = (ay + by) * wi + bb.y;
  if (DO_ELU) {
    rx = rx > 0.f ? rx : expm1f(rx);
    ry = ry > 0.f ? ry : expm1f(ry);
  }
  ((float2*)outp)[(size_t)node * 64 + lane] = make_float2(rx, ry);
}

template<bool DO_ELU>
__global__ __launch_bounds__(256) void aggr1_k(const float* __restrict__ xl,
                                               const float* __restrict__ alphaE,
                                               const float* __restrict__ alphaSelf,
                                               const float* __restrict__ invArr,
                                               const float* __restrict__ bias,
                                               const int* __restrict__ row_ptr,
                                               const int* __restrict__ csr,
                                               float* __restrict__ outp, int n) {
  const int node = blockIdx.x * 4 + (threadIdx.x >> 6);
  const int lane = threadIdx.x & 63;
  if (node >= n) return;
  const int row = row_ptr[node];
  const int deg = row_ptr[node + 1] - row;
  float ax = 0.f, bx = 0.f;
  int j = 0;
  for (; j + 4 <= deg; j += 4) {
    int s0 = csr[row + j], s1 = csr[row + j + 1], s2 = csr[row + j + 2], s3 = csr[row + j + 3];
    float a0 = alphaE[row + j], a1 = alphaE[row + j + 1];
    float a2 = alphaE[row + j + 2], a3 = alphaE[row + j + 3];
    float v0 = xl[(size_t)s0 * 64 + lane];
    float v1 = xl[(size_t)s1 * 64 + lane];
    float v2 = xl[(size_t)s2 * 64 + lane];
    float v3 = xl[(size_t)s3 * 64 + lane];
    ax += a0 * v0; bx += a1 * v1;
    ax += a2 * v2; bx += a3 * v3;
  }
  for (; j < deg; ++j) {
    ax += alphaE[row + j] * xl[(size_t)csr[row + j] * 64 + lane];
  }
  float r = (ax + bx + alphaSelf[node] * xl[(size_t)node * 64 + lane]) * invArr[node] + bias[lane];
  if (DO_ELU) r = r > 0.f ? r : expm1f(r);
  outp[(size_t)node * 64 + lane] = r;
}

// ---------------- launch ----------------

extern "C" void kernel_launch(void* const* d_in, const int* in_sizes, int n_in,
                              void* d_out, int out_size, void* d_ws, size_t ws_size,
                              hipStream_t stream) {
  const float* x  = (const float*)d_in[0];
  const int* ei   = (const int*)d_in[1];
  const float* W0 = (const float*)d_in[2];
  const float* as0 = (const float*)d_in[3];
  const float* ad0 = (const float*)d_in[4];
  const float* b0 = (const float*)d_in[5];
  const float* W1 = (const float*)d_in[6];
  const float* as1 = (const float*)d_in[7];
  const float* ad1 = (const float*)d_in[8];
  const float* b1 = (const float*)d_in[9];
  const float* W2 = (const float*)d_in[10];
  const float* as2 = (const float*)d_in[11];
  const float* ad2 = (const float*)d_in[12];
  const float* b2 = (const float*)d_in[13];
  float* out = (float*)d_out;

  const int n = in_sizes[0] / 128;
  const int e = in_sizes[1] / 2;
  const int* srcIdx = ei;
  const int* dstIdx = ei + e;

  float* ws = (float*)d_ws;
  float* bufA = ws;                                 // n*128 (xl)
  float* bufB = bufA + (size_t)n * 128;             // n*128 (layer output)
  float* sArr = bufB + (size_t)n * 128;             // n*2
  float* dArr = sArr + (size_t)n * 2;               // n*2
  float* alphaSelf = dArr + (size_t)n * 2;          // n*2
  float* invArr = alphaSelf + (size_t)n * 2;        // n*2
  float* alphaE = invArr + (size_t)n * 2;           // e*2
  int* row_ptr = (int*)(alphaE + (size_t)e * 2);    // n+1
  int* cursor = row_ptr + (n + 1);                  // n
  int* csr = cursor + n;                            // e

  // CSR build (shared by all 3 layers)
  hipMemsetAsync(cursor, 0, (size_t)n * sizeof(int), stream);
  count_dst_k<<<(e + 255) / 256, 256, 0, stream>>>(dstIdx, cursor, e);
  scan_k<<<1, 1024, 0, stream>>>(cursor, row_ptr, n);
  scatter_k<<<(e + 255) / 256, 256, 0, stream>>>(srcIdx, dstIdx, cursor, csr, e);

  const int gb = (n + 63) / 64;
  const int gp2 = (n * 2 + 3) / 4;  // H=2 pair-grid (attn)
  const int gp1 = (n + 3) / 4;      // node-grid

  // layer 0
  gemm_k<128><<<gb, 256, 0, stream>>>(x, W0, bufA, n);
  attn_k<2><<<gp2, 256, 0, stream>>>(bufA, as0, ad0, sArr, dArr, n);
  softmax2_k<<<gp1, 256, 0, stream>>>(sArr, dArr, row_ptr, csr, alphaE, alphaSelf, invArr, n);
  aggr2_k<true><<<gp1, 256, 0, stream>>>(bufA, alphaE, alphaSelf, invArr, b0, row_ptr, csr, bufB, n);

  // layer 1
  gemm_k<128><<<gb, 256, 0, stream>>>(bufB, W1, bufA, n);
  attn_k<2><<<gp2, 256, 0, stream>>>(bufA, as1, ad1, sArr, dArr, n);
  softmax2_k<<<gp1, 256, 0, stream>>>(sArr, dArr, row_ptr, csr, alphaE, alphaSelf, invArr, n);
  aggr2_k<true><<<gp1, 256, 0, stream>>>(bufA, alphaE, alphaSelf, invArr, b1, row_ptr, csr, bufB, n);

  // layer 2 (H=1, no concat, no elu)
  gemm_k<64><<<gb, 256, 0, stream>>>(bufB, W2, bufA, n);
  attn_k<1><<<gp1, 256, 0, stream>>>(bufA, as2, ad2, sArr, dArr, n);
  softmax1_k<<<gp1, 256, 0, stream>>>(sArr, dArr, row_ptr, csr, alphaE, alphaSelf, invArr, n);
  aggr1_k<false><<<gp1, 256, 0, stream>>>(bufA, alphaE, alphaSelf, invArr, b2, row_ptr, csr, out, n);
}

// Round 4
// 585.984 us; speedup vs baseline: 1.5788x; 1.1943x over previous
//
#include <hip/hip_runtime.h>
#include <math.h>

#define NEG_SLOPE 0.2f

__device__ __forceinline__ float lrelu(float v) { return v > 0.0f ? v : NEG_SLOPE * v; }

// ---------------- CSR build ----------------

__global__ void count_dst_k(const int* __restrict__ dst, int* __restrict__ counts, int e) {
  int i = blockIdx.x * 256 + threadIdx.x;
  if (i < e) atomicAdd(&counts[dst[i]], 1);
}

// Hierarchical exclusive scan over counts (n elements, 256/block).
// 1) per-block sums
__global__ __launch_bounds__(256) void block_sum_k(const int* __restrict__ counts,
                                                   int* __restrict__ blockSums, int n) {
  int i = blockIdx.x * 256 + threadIdx.x;
  int v = (i < n) ? counts[i] : 0;
  for (int o = 32; o > 0; o >>= 1) v += __shfl_xor(v, o);
  __shared__ int ws[4];
  if ((threadIdx.x & 63) == 0) ws[threadIdx.x >> 6] = v;
  __syncthreads();
  if (threadIdx.x == 0) blockSums[blockIdx.x] = ws[0] + ws[1] + ws[2] + ws[3];
}

// 2) single-block exclusive scan of block sums; total -> *total_out
__global__ __launch_bounds__(256) void scan_sums_k(int* __restrict__ blockSums, int nb,
                                                   int* __restrict__ total_out) {
  __shared__ int sh[256];
  const int tid = threadIdx.x;
  int run = 0;
  for (int base = 0; base < nb; base += 256) {
    int i = base + tid;
    int v = (i < nb) ? blockSums[i] : 0;
    sh[tid] = v;
    __syncthreads();
    for (int o = 1; o < 256; o <<= 1) {
      int t = (tid >= o) ? sh[tid - o] : 0;
      __syncthreads();
      sh[tid] += t;
      __syncthreads();
    }
    int chunkTotal = sh[255];
    if (i < nb) blockSums[i] = run + sh[tid] - v;
    __syncthreads();
    run += chunkTotal;
  }
  if (tid == 0) *total_out = run;
}

// 3) per-block re-scan + apply offset; writes row_ptr and cursor (aliases counts).
__global__ __launch_bounds__(256) void scan_apply_k(int* __restrict__ counts_cursor,
                                                    const int* __restrict__ blockOffs,
                                                    int* __restrict__ row_ptr, int n) {
  __shared__ int sh[256];
  const int tid = threadIdx.x;
  const int i = blockIdx.x * 256 + tid;
  int v = (i < n) ? counts_cursor[i] : 0;
  sh[tid] = v;
  __syncthreads();
  for (int o = 1; o < 256; o <<= 1) {
    int t = (tid >= o) ? sh[tid - o] : 0;
    __syncthreads();
    sh[tid] += t;
    __syncthreads();
  }
  if (i < n) {
    int excl = blockOffs[blockIdx.x] + sh[tid] - v;
    row_ptr[i] = excl;
    counts_cursor[i] = excl;
  }
}

__global__ void scatter_k(const int* __restrict__ src, const int* __restrict__ dst,
                          int* __restrict__ cursor, int* __restrict__ csr, int e) {
  int i = blockIdx.x * 256 + threadIdx.x;
  if (i < e) {
    int pos = atomicAdd(&cursor[dst[i]], 1);
    csr[pos] = src[i];
  }
}

// ---------------- GEMM: Y[n,M] = X[n,128] @ W[128,M] ----------------

template<int M>
__global__ __launch_bounds__(256) void gemm_k(const float* __restrict__ X,
                                              const float* __restrict__ W,
                                              float* __restrict__ Y, int n) {
  constexpr int NC4 = M / 4;
  constexpr int NTY = 256 / NC4;
  constexpr int RPT = 64 / NTY;
  __shared__ float4 ws4[32 * NC4];
  __shared__ float4 xs4[64 * 8];
  const int tid = threadIdx.x;
  const int tx = tid % NC4;
  const int ty = tid / NC4;
  const int rb = blockIdx.x * 64;
  float acc[RPT][4];
  for (int i = 0; i < RPT; ++i)
    for (int j = 0; j < 4; ++j) acc[i][j] = 0.f;

  for (int kc = 0; kc < 4; ++kc) {
    const float4* Wp = (const float4*)(W + (size_t)kc * 32 * M);
    for (int i = tid; i < 32 * NC4; i += 256) ws4[i] = Wp[i];
    for (int i = tid; i < 64 * 8; i += 256) {
      int r = i >> 3, c4 = i & 7;
      int row = rb + r;
      float4 v = make_float4(0.f, 0.f, 0.f, 0.f);
      if (row < n) v = *(const float4*)(X + (size_t)row * 128 + kc * 32 + c4 * 4);
      xs4[i] = v;
    }
    __syncthreads();
    for (int k4 = 0; k4 < 8; ++k4) {
      float4 xv[RPT];
      for (int i = 0; i < RPT; ++i) xv[i] = xs4[(ty + i * NTY) * 8 + k4];
      float4 wv[4];
      for (int dk = 0; dk < 4; ++dk) wv[dk] = ws4[(k4 * 4 + dk) * NC4 + tx];
      for (int i = 0; i < RPT; ++i) {
        acc[i][0] += xv[i].x * wv[0].x + xv[i].y * wv[1].x + xv[i].z * wv[2].x + xv[i].w * wv[3].x;
        acc[i][1] += xv[i].x * wv[0].y + xv[i].y * wv[1].y + xv[i].z * wv[2].y + xv[i].w * wv[3].y;
        acc[i][2] += xv[i].x * wv[0].z + xv[i].y * wv[1].z + xv[i].z * wv[2].z + xv[i].w * wv[3].z;
        acc[i][3] += xv[i].x * wv[0].w + xv[i].y * wv[1].w + xv[i].z * wv[2].w + xv[i].w * wv[3].w;
      }
    }
    __syncthreads();
  }
  for (int i = 0; i < RPT; ++i) {
    int row = rb + ty + i * NTY;
    if (row < n)
      *(float4*)(Y + (size_t)row * M + tx * 4) =
          make_float4(acc[i][0], acc[i][1], acc[i][2], acc[i][3]);
  }
}

// ---------------- attention coefficients: s/d per (node,head) ----------------

template<int H_>
__global__ __launch_bounds__(256) void attn_k(const float* __restrict__ xl,
                                              const float* __restrict__ a_src,
                                              const float* __restrict__ a_dst,
                                              float* __restrict__ sArr,
                                              float* __restrict__ dArr, int n) {
  const int pair = blockIdx.x * 4 + (threadIdx.x >> 6);
  const int lane = threadIdx.x & 63;
  if (pair >= n * H_) return;
  const int h = pair % H_;
  float v = xl[(size_t)pair * 64 + lane];
  float sv = v * a_src[h * 64 + lane];
  float dv = v * a_dst[h * 64 + lane];
  for (int o = 32; o > 0; o >>= 1) {
    sv += __shfl_xor(sv, o);
    dv += __shfl_xor(dv, o);
  }
  if (lane == 0) {
    sArr[pair] = sv;
    dArr[pair] = dv;
  }
}

// ---------------- softmax precompute ----------------

__global__ __launch_bounds__(256) void softmax2_k(const float* __restrict__ sArr,
                                                  const float* __restrict__ dArr,
                                                  const int* __restrict__ row_ptr,
                                                  const int* __restrict__ csr,
                                                  float* __restrict__ alphaE,
                                                  float* __restrict__ alphaSelf,
                                                  float* __restrict__ invArr, int n) {
  const int node = blockIdx.x * 4 + (threadIdx.x >> 6);
  const int lane = threadIdx.x & 63;
  if (node >= n) return;
  const int row = row_ptr[node];
  const int deg = row_ptr[node + 1] - row;
  const float2 dn = ((const float2*)dArr)[node];
  const float2 sn = ((const float2*)sArr)[node];
  const float e0s = lrelu(sn.x + dn.x), e1s = lrelu(sn.y + dn.y);
  float m0 = e0s, m1 = e1s;
  for (int j = lane; j < deg; j += 64) {
    int sj = csr[row + j];
    float2 sv = ((const float2*)sArr)[sj];
    m0 = fmaxf(m0, lrelu(sv.x + dn.x));
    m1 = fmaxf(m1, lrelu(sv.y + dn.y));
  }
  for (int o = 32; o > 0; o >>= 1) {
    m0 = fmaxf(m0, __shfl_xor(m0, o));
    m1 = fmaxf(m1, __shfl_xor(m1, o));
  }
  float s0 = 0.f, s1 = 0.f;
  for (int j = lane; j < deg; j += 64) {
    int sj = csr[row + j];
    float2 sv = ((const float2*)sArr)[sj];
    float x0 = __expf(lrelu(sv.x + dn.x) - m0);
    float x1 = __expf(lrelu(sv.y + dn.y) - m1);
    ((float2*)alphaE)[row + j] = make_float2(x0, x1);
    s0 += x0;
    s1 += x1;
  }
  for (int o = 32; o > 0; o >>= 1) {
    s0 += __shfl_xor(s0, o);
    s1 += __shfl_xor(s1, o);
  }
  float xs0 = __expf(e0s - m0), xs1 = __expf(e1s - m1);
  s0 += xs0;
  s1 += xs1;
  if (lane == 0) {
    ((float2*)alphaSelf)[node] = make_float2(xs0, xs1);
    ((float2*)invArr)[node] = make_float2(1.f / s0, 1.f / s1);
  }
}

__global__ __launch_bounds__(256) void softmax1_k(const float* __restrict__ sArr,
                                                  const float* __restrict__ dArr,
                                                  const int* __restrict__ row_ptr,
                                                  const int* __restrict__ csr,
                                                  float* __restrict__ alphaE,
                                                  float* __restrict__ alphaSelf,
                                                  float* __restrict__ invArr, int n) {
  const int node = blockIdx.x * 4 + (threadIdx.x >> 6);
  const int lane = threadIdx.x & 63;
  if (node >= n) return;
  const int row = row_ptr[node];
  const int deg = row_ptr[node + 1] - row;
  const float dn = dArr[node];
  const float es = lrelu(sArr[node] + dn);
  float m = es;
  for (int j = lane; j < deg; j += 64) {
    int sj = csr[row + j];
    m = fmaxf(m, lrelu(sArr[sj] + dn));
  }
  for (int o = 32; o > 0; o >>= 1) m = fmaxf(m, __shfl_xor(m, o));
  float s = 0.f;
  for (int j = lane; j < deg; j += 64) {
    int sj = csr[row + j];
    float x = __expf(lrelu(sArr[sj] + dn) - m);
    alphaE[row + j] = x;
    s += x;
  }
  for (int o = 32; o > 0; o >>= 1) s += __shfl_xor(s, o);
  float xs = __expf(es - m);
  s += xs;
  if (lane == 0) {
    alphaSelf[node] = xs;
    invArr[node] = 1.f / s;
  }
}

// ---------------- aggregation ----------------

template<bool DO_ELU>
__global__ __launch_bounds__(256) void aggr2_k(const float* __restrict__ xl,
                                               const float* __restrict__ alphaE,
                                               const float* __restrict__ alphaSelf,
                                               const float* __restrict__ invArr,
                                               const float* __restrict__ bias,
                                               const int* __restrict__ row_ptr,
                                               const int* __restrict__ csr,
                                               float* __restrict__ outp, int n) {
  const int node = blockIdx.x * 4 + (threadIdx.x >> 6);
  const int lane = threadIdx.x & 63;
  if (node >= n) return;
  const int row = row_ptr[node];
  const int deg = row_ptr[node + 1] - row;
  const float2* __restrict__ xl2 = (const float2*)xl;
  const float2* __restrict__ aE = (const float2*)alphaE;
  const bool lo = lane < 32;
  float ax = 0.f, ay = 0.f, bx = 0.f, by = 0.f;
  int j = 0;
  for (; j + 4 <= deg; j += 4) {
    int s0 = csr[row + j], s1 = csr[row + j + 1], s2 = csr[row + j + 2], s3 = csr[row + j + 3];
    float2 a0 = aE[row + j], a1 = aE[row + j + 1], a2 = aE[row + j + 2], a3 = aE[row + j + 3];
    float2 v0 = xl2[(size_t)s0 * 64 + lane];
    float2 v1 = xl2[(size_t)s1 * 64 + lane];
    float2 v2 = xl2[(size_t)s2 * 64 + lane];
    float2 v3 = xl2[(size_t)s3 * 64 + lane];
    float w0 = lo ? a0.x : a0.y, w1 = lo ? a1.x : a1.y;
    float w2 = lo ? a2.x : a2.y, w3 = lo ? a3.x : a3.y;
    ax += w0 * v0.x; ay += w0 * v0.y;
    bx += w1 * v1.x; by += w1 * v1.y;
    ax += w2 * v2.x; ay += w2 * v2.y;
    bx += w3 * v3.x; by += w3 * v3.y;
  }
  for (; j < deg; ++j) {
    int sj = csr[row + j];
    float2 a = aE[row + j];
    float2 v = xl2[(size_t)sj * 64 + lane];
    float w = lo ? a.x : a.y;
    ax += w * v.x; ay += w * v.y;
  }
  float2 aS = ((const float2*)alphaSelf)[node];
  float2 vS = xl2[(size_t)node * 64 + lane];
  float wS = lo ? aS.x : aS.y;
  ax += wS * vS.x; ay += wS * vS.y;
  float2 iv = ((const float2*)invArr)[node];
  float wi = lo ? iv.x : iv.y;
  float2 bb = ((const float2*)bias)[lane];
  float rx = (ax + bx) * wi + bb.x;
  float ry = (ay + by) * wi + bb.y;
  if (DO_ELU) {
    rx = rx > 0.f ? rx : expm1f(rx);
    ry = ry > 0.f ? ry : expm1f(ry);
  }
  ((float2*)outp)[(size_t)node * 64 + lane] = make_float2(rx, ry);
}

template<bool DO_ELU>
__global__ __launch_bounds__(256) void aggr1_k(const float* __restrict__ xl,
                                               const float* __restrict__ alphaE,
                                               const float* __restrict__ alphaSelf,
                                               const float* __restrict__ invArr,
                                               const float* __restrict__ bias,
                                               const int* __restrict__ row_ptr,
                                               const int* __restrict__ csr,
                                               float* __restrict__ outp, int n) {
  const int node = blockIdx.x * 4 + (threadIdx.x >> 6);
  const int lane = threadIdx.x & 63;
  if (node >= n) return;
  const int row = row_ptr[node];
  const int deg = row_ptr[node + 1] - row;
  float ax = 0.f, bx = 0.f;
  int j = 0;
  for (; j + 4 <= deg; j += 4) {
    int s0 = csr[row + j], s1 = csr[row + j + 1], s2 = csr[row + j + 2], s3 = csr[row + j + 3];
    float a0 = alphaE[row + j], a1 = alphaE[row + j + 1];
    float a2 = alphaE[row + j + 2], a3 = alphaE[row + j + 3];
    float v0 = xl[(size_t)s0 * 64 + lane];
    float v1 = xl[(size_t)s1 * 64 + lane];
    float v2 = xl[(size_t)s2 * 64 + lane];
    float v3 = xl[(size_t)s3 * 64 + lane];
    ax += a0 * v0; bx += a1 * v1;
    ax += a2 * v2; bx += a3 * v3;
  }
  for (; j < deg; ++j) {
    ax += alphaE[row + j] * xl[(size_t)csr[row + j] * 64 + lane];
  }
  float r = (ax + bx + alphaSelf[node] * xl[(size_t)node * 64 + lane]) * invArr[node] + bias[lane];
  if (DO_ELU) r = r > 0.f ? r : expm1f(r);
  outp[(size_t)node * 64 + lane] = r;
}

// ---------------- launch ----------------

extern "C" void kernel_launch(void* const* d_in, const int* in_sizes, int n_in,
                              void* d_out, int out_size, void* d_ws, size_t ws_size,
                              hipStream_t stream) {
  const float* x  = (const float*)d_in[0];
  const int* ei   = (const int*)d_in[1];
  const float* W0 = (const float*)d_in[2];
  const float* as0 = (const float*)d_in[3];
  const float* ad0 = (const float*)d_in[4];
  const float* b0 = (const float*)d_in[5];
  const float* W1 = (const float*)d_in[6];
  const float* as1 = (const float*)d_in[7];
  const float* ad1 = (const float*)d_in[8];
  const float* b1 = (const float*)d_in[9];
  const float* W2 = (const float*)d_in[10];
  const float* as2 = (const float*)d_in[11];
  const float* ad2 = (const float*)d_in[12];
  const float* b2 = (const float*)d_in[13];
  float* out = (float*)d_out;

  const int n = in_sizes[0] / 128;
  const int e = in_sizes[1] / 2;
  const int* srcIdx = ei;
  const int* dstIdx = ei + e;

  float* ws = (float*)d_ws;
  float* bufA = ws;                                 // n*128 (xl)
  float* bufB = bufA + (size_t)n * 128;             // n*128 (layer output)
  float* sArr = bufB + (size_t)n * 128;             // n*2
  float* dArr = sArr + (size_t)n * 2;               // n*2
  float* alphaSelf = dArr + (size_t)n * 2;          // n*2
  float* invArr = alphaSelf + (size_t)n * 2;        // n*2
  float* alphaE = invArr + (size_t)n * 2;           // e*2
  int* row_ptr = (int*)(alphaE + (size_t)e * 2);    // n+1
  int* cursor = row_ptr + (n + 1);                  // n
  int* csr = cursor + n;                            // e
  int* blockSums = csr + e;                         // nb

  const int nb = (n + 255) / 256;

  // CSR build (shared by all 3 layers)
  hipMemsetAsync(cursor, 0, (size_t)n * sizeof(int), stream);
  count_dst_k<<<(e + 255) / 256, 256, 0, stream>>>(dstIdx, cursor, e);
  block_sum_k<<<nb, 256, 0, stream>>>(cursor, blockSums, n);
  scan_sums_k<<<1, 256, 0, stream>>>(blockSums, nb, row_ptr + n);
  scan_apply_k<<<nb, 256, 0, stream>>>(cursor, blockSums, row_ptr, n);
  scatter_k<<<(e + 255) / 256, 256, 0, stream>>>(srcIdx, dstIdx, cursor, csr, e);

  const int gb = (n + 63) / 64;
  const int gp2 = (n * 2 + 3) / 4;
  const int gp1 = (n + 3) / 4;

  // layer 0
  gemm_k<128><<<gb, 256, 0, stream>>>(x, W0, bufA, n);
  attn_k<2><<<gp2, 256, 0, stream>>>(bufA, as0, ad0, sArr, dArr, n);
  softmax2_k<<<gp1, 256, 0, stream>>>(sArr, dArr, row_ptr, csr, alphaE, alphaSelf, invArr, n);
  aggr2_k<true><<<gp1, 256, 0, stream>>>(bufA, alphaE, alphaSelf, invArr, b0, row_ptr, csr, bufB, n);

  // layer 1
  gemm_k<128><<<gb, 256, 0, stream>>>(bufB, W1, bufA, n);
  attn_k<2><<<gp2, 256, 0, stream>>>(bufA, as1, ad1, sArr, dArr, n);
  softmax2_k<<<gp1, 256, 0, stream>>>(sArr, dArr, row_ptr, csr, alphaE, alphaSelf, invArr, n);
  aggr2_k<true><<<gp1, 256, 0, stream>>>(bufA, alphaE, alphaSelf, invArr, b1, row_ptr, csr, bufB, n);

  // layer 2 (H=1, no concat, no elu)
  gemm_k<64><<<gb, 256, 0, stream>>>(bufB, W2, bufA, n);
  attn_k<1><<<gp1, 256, 0, stream>>>(bufA, as2, ad2, sArr, dArr, n);
  softmax1_k<<<gp1, 256, 0, stream>>>(sArr, dArr, row_ptr, csr, alphaE, alphaSelf, invArr, n);
  aggr1_k<false><<<gp1, 256, 0, stream>>>(bufA, alphaE, alphaSelf, invArr, b2, row_ptr, csr, out, n);
}